// Round 3
// baseline (849.527 us; speedup 1.0000x reference)
//
#include <hip/hip_runtime.h>
#include <hip/hip_bf16.h>

// Bahdanau attention, MI355X. B=32, T=2048, D=1024, U=1024.
// R6 = R5 resubmitted verbatim after audit (R5 bench died to container infra,
// no kernel evidence; hazard/bounds/register audit found no defect).
// R5: score GEMM restructured for LDS<->MFMA overlap ("read-ahead" schedule).
// R4's 8-phase port fixed bank conflicts (1.7e7 -> 0) but each phase still
// serialized [ds_read service (~1000cyc/CU)] -> lgkmcnt(0) -> [MFMA (621cyc)].
// Now every phase issues ds_reads for a LATER phase into disjoint regs
// (afA/afB ping-pong + bfr01/bfr23 alternation) and waits with COUNTED
// lgkmcnt(4/8) so in-flight reads overlap the MFMA cluster:
//   ph0: rd bfr23(cur)      [4]  lgkm(4)  MFMA afA x bfr01   + STA(t+1)h0
//   ph1: rd afB (cur,r64+)  [8]  lgkm(8)  MFMA afA x bfr23   + STA(t+1)h1  BAR
//   ph2:                    [0]  lgkm(0)  MFMA afB x bfr01   + STB(t+2)h0  vmcnt(2) BAR
//   ph3: rd afA'+bfr01'(nxt)[12]  (none)  MFMA afB x bfr23   + STB(t+2)h1
// vmcnt(2)@ph2 guarantees A(t+1),B(t+1) landed before ph3's next-buffer reads.
// Counted lgkm is sound: global_load_lds completion is vmcnt-only (CDNA ISA);
// DS ops retire in order among themselves.
// R5b: context_kernel reads valb bf16 (halves its HBM traffic).

typedef __bf16 bf16x8 __attribute__((ext_vector_type(8)));
typedef __bf16 bf16x4 __attribute__((ext_vector_type(4)));
typedef short  s16x8  __attribute__((ext_vector_type(8)));
typedef float  f32x4  __attribute__((ext_vector_type(4)));

#define B_  32
#define T_  2048
#define D_  1024
#define U_  1024
#define BT_ (B_*T_)

// ws layout (bytes)
#define WS_W1T    ((size_t)0)                          // 2 MiB bf16 [U][D]
#define WS_PROJQ  ((size_t)(2u*1024*1024))             // 128 KiB fp32 [B][U]
#define WS_SCORE  ((size_t)(2u*1024*1024 + 128u*1024)) // 256 KiB fp32 [B*T]
#define WS_VALB   ((size_t)(4u*1024*1024))             // 128 MiB bf16 [BT][D]
#define WS_NEEDED (WS_VALB + (size_t)BT_ * D_ * 2)

__device__ __forceinline__ float tanh_fast(float x) {
    const float e = __expf(2.0f * x);
    return 1.0f - __fdividef(2.0f, e + 1.0f);
}

__device__ __forceinline__ void glls16(const void* g, void* l) {
    __builtin_amdgcn_global_load_lds(
        (const __attribute__((address_space(1))) void*)g,
        (__attribute__((address_space(3))) void*)l, 16, 0, 0);
}

// ---------------- init: projq = b1+b2 (broadcast), score = 0 ----------------
__global__ void init_kernel(const float* __restrict__ b1, const float* __restrict__ b2,
                            float* __restrict__ projq, float* __restrict__ score) {
    int i = blockIdx.x * 256 + threadIdx.x;       // grid 384*256 = 98304 exact
    if (i < B_ * U_) {
        projq[i] = b1[i & (U_ - 1)] + b2[i & (U_ - 1)];
    } else {
        score[i - B_ * U_] = 0.0f;
    }
}

// ---------------- values fp32 -> bf16 (streaming) ----------------
__global__ void convert_kernel(const float* __restrict__ v, __bf16* __restrict__ o) {
    const size_t i = ((size_t)blockIdx.x * 256 + threadIdx.x) * 8;   // grid 32768
    const float4 a = *(const float4*)(v + i);
    const float4 b = *(const float4*)(v + i + 4);
    bf16x8 h;
    h[0] = (__bf16)a.x; h[1] = (__bf16)a.y; h[2] = (__bf16)a.z; h[3] = (__bf16)a.w;
    h[4] = (__bf16)b.x; h[5] = (__bf16)b.y; h[6] = (__bf16)b.z; h[7] = (__bf16)b.w;
    *(bf16x8*)(o + i) = h;
}

// ---------------- W1 [D][U] fp32 -> W1T [U][D] bf16 ----------------
__global__ void w1_transpose_kernel(const float* __restrict__ W1, __bf16* __restrict__ W1T) {
    __shared__ float tile[64][65];
    const int bx = blockIdx.x & 15;   // u tile
    const int by = blockIdx.x >> 4;   // d tile
    const int tid = threadIdx.x;      // 256
    const int j  = tid & 63;
    const int i0 = tid >> 6;          // 0..3
#pragma unroll
    for (int p = 0; p < 16; ++p) {
        const int i = i0 + p * 4;
        tile[i][j] = W1[(size_t)(by * 64 + i) * U_ + bx * 64 + j];
    }
    __syncthreads();
#pragma unroll
    for (int p = 0; p < 16; ++p) {
        const int i = i0 + p * 4;     // local u row
        W1T[(size_t)(bx * 64 + i) * D_ + by * 64 + j] = (__bf16)tile[j][i];
    }
}

// ---------------- projq += query @ W2 (fp32, d-split + atomics) ----------------
__global__ void projq_kernel(const float* __restrict__ query, const float* __restrict__ W2,
                             float* __restrict__ projq) {
    __shared__ float q[128];
    const int b  = blockIdx.x >> 3;   // 32
    const int dc = blockIdx.x & 7;    // 8 chunks of 128 d
    const int tid = threadIdx.x;      // 256
    if (tid < 128) q[tid] = query[(size_t)b * D_ + dc * 128 + tid];
    __syncthreads();
    const int u0 = tid * 4;
    float a0 = 0.f, a1 = 0.f, a2 = 0.f, a3 = 0.f;
    for (int d = 0; d < 128; ++d) {
        const float4 w = *(const float4*)(W2 + (size_t)(dc * 128 + d) * U_ + u0);
        const float qd = q[d];
        a0 = fmaf(qd, w.x, a0); a1 = fmaf(qd, w.y, a1);
        a2 = fmaf(qd, w.z, a2); a3 = fmaf(qd, w.w, a3);
    }
    float* p = projq + (size_t)b * U_ + u0;
    atomicAdd(p + 0, a0); atomicAdd(p + 1, a1);
    atomicAdd(p + 2, a2); atomicAdd(p + 3, a3);
}

// ---------------- fused score GEMM: 256^2 read-ahead schedule ----------------
// Grid 1024 = 256 mblk x 4 nblk, XCD-swizzled. 512 threads = 8 waves (2M x 4N);
// wave output 128x64. LDS: 2 buffers x {A 256x64, B 256x64} bf16 = 128 KiB,
// XOR swizzle byte^=((row&7)<<4) via pre-swizzled global src + swizzled ds_read.
// Staging per tile t (cur buf c): ph0/ph1: A(t+1)->c^1; ph2/ph3: B(t+2)->c.

#define SC_LDSB 32768   // elements per LDS buffer (64 KiB); A at +0, B at +16384

__global__ __launch_bounds__(512, 2)
void score_kernel_ra(const __bf16* __restrict__ valb, const __bf16* __restrict__ W1T,
                     const float* __restrict__ projq, const float* __restrict__ V,
                     float* __restrict__ score) {
    __shared__ __attribute__((aligned(16))) __bf16 lds[2 * SC_LDSB];  // 128 KiB

    const int tid  = threadIdx.x;
    const int bid  = blockIdx.x;
    const int xcd  = bid & 7;
    const int sl   = bid >> 3;            // 0..127
    const int mblk = xcd * 32 + (sl >> 2);
    const int nblk = sl & 3;

    const int wv   = tid >> 6;            // wave 0..7
    const int lane = tid & 63;
    const int wm   = wv >> 2;             // 0..1 : A half
    const int wn   = wv & 3;              // 0..3 : 64-col slice of B
    const int l15  = lane & 15, quad = lane >> 4;
    const int e    = l15 & 7;
    const int sl0  = ((quad)     ^ e) * 8;   // swizzled slot, kstep 0
    const int sl1  = ((quad + 4) ^ e) * 8;   // swizzled slot, kstep 1
    const int offA0 = wm * 8192 + l15 * 64 + sl0;
    const int offA1 = wm * 8192 + l15 * 64 + sl1;
    const int offB0 = 16384 + (wn >> 1) * 8192 + ((wn & 1) * 64 + l15) * 64 + sl0;
    const int offB1 = 16384 + (wn >> 1) * 8192 + ((wn & 1) * 64 + l15) * 64 + sl1;

    // staging: lane covers phys row (wv*8 + lane>>3), phys slot (lane&7);
    // logical (pre-swizzled) source slot = (lane&7) ^ (row&7)
    const int srow = lane >> 3;
    const int scol = ((lane & 7) ^ srow) * 8;
    const __bf16* aS = valb + ((size_t)mblk * 256 + wv * 8 + srow) * D_ + scol;
    const __bf16* bS = W1T  + ((size_t)nblk * 256 + wv * 8 + srow) * D_ + scol;
    __bf16* aD = lds + wv * 512;            // wave-uniform linear dest bases
    __bf16* bD = lds + 16384 + wv * 512;

#define DSR(dst, off) do { s16x8 _t;                                            \
    asm volatile("ds_read_b128 %0, %1" : "=v"(_t)                              \
        : "v"((const __attribute__((address_space(3))) __bf16*)(lds + (off)))); \
    (dst) = __builtin_bit_cast(bf16x8, _t); } while (0)

#define STA(CB, H, KT) do {                                                     \
    glls16(aS + (size_t)((H)*128     ) * D_ + (KT)*64, aD + (CB) + (H)*8192);        \
    glls16(aS + (size_t)((H)*128 + 64) * D_ + (KT)*64, aD + (CB) + (H)*8192 + 4096); \
    } while (0)
#define STB(CB, H, KT) do {                                                     \
    glls16(bS + (size_t)((H)*128     ) * D_ + (KT)*64, bD + (CB) + (H)*8192);        \
    glls16(bS + (size_t)((H)*128 + 64) * D_ + (KT)*64, bD + (CB) + (H)*8192 + 4096); \
    } while (0)

#define MQG(AF, ML, NL) do {                                                    \
    _Pragma("unroll") for (int mi = 0; mi < 4; ++mi)                            \
    _Pragma("unroll") for (int ni = 0; ni < 2; ++ni) {                          \
        acc[(ML)+mi][(NL)+ni] = __builtin_amdgcn_mfma_f32_16x16x32_bf16(        \
            AF[mi][0], bfr[(NL)+ni][0], acc[(ML)+mi][(NL)+ni], 0, 0, 0);        \
        acc[(ML)+mi][(NL)+ni] = __builtin_amdgcn_mfma_f32_16x16x32_bf16(        \
            AF[mi][1], bfr[(NL)+ni][1], acc[(ML)+mi][(NL)+ni], 0, 0, 0);        \
    } } while (0)

// lgkm counting (per wave, DS ops retire in order):
//  entering ph0: 12 outstanding (ph3's afA'+bfr01'); +4 -> lgkm(4) drains them.
//  ph1: +8 -> 12 outstanding; lgkm(8) drains bfr23.  ph2: lgkm(0) drains afB.
//  ph3's 12 reads drain at next tile's ph0 lgkm(4).
#define TILE(KT, CB, DOA, DOB, VMS, DORD) do {                                  \
    /* ph0 */                                                                   \
    DSR(bfr[2][0], (CB) + offB0 + 2*1024);                                      \
    DSR(bfr[2][1], (CB) + offB1 + 2*1024);                                      \
    DSR(bfr[3][0], (CB) + offB0 + 3*1024);                                      \
    DSR(bfr[3][1], (CB) + offB1 + 3*1024);                                      \
    if (DOA) STA((CB) ^ SC_LDSB, 0, (KT) + 1);                                  \
    asm volatile("s_waitcnt lgkmcnt(4)" ::: "memory");                          \
    __builtin_amdgcn_sched_barrier(0);                                          \
    __builtin_amdgcn_s_setprio(1); MQG(afA, 0, 0); __builtin_amdgcn_s_setprio(0);\
    /* ph1 */                                                                   \
    _Pragma("unroll") for (int m = 0; m < 4; ++m) {                             \
        DSR(afB[m][0], (CB) + offA0 + (4 + m) * 1024);                          \
        DSR(afB[m][1], (CB) + offA1 + (4 + m) * 1024); }                        \
    if (DOA) STA((CB) ^ SC_LDSB, 1, (KT) + 1);                                  \
    asm volatile("s_waitcnt lgkmcnt(8)" ::: "memory");                          \
    __builtin_amdgcn_sched_barrier(0);                                          \
    __builtin_amdgcn_s_setprio(1); MQG(afA, 0, 2); __builtin_amdgcn_s_setprio(0);\
    __builtin_amdgcn_s_barrier();                                               \
    /* ph2 */                                                                   \
    if (DOB) STB((CB), 0, (KT) + 2);                                            \
    asm volatile("s_waitcnt lgkmcnt(0)" ::: "memory");                          \
    __builtin_amdgcn_sched_barrier(0);                                          \
    __builtin_amdgcn_s_setprio(1); MQG(afB, 4, 0); __builtin_amdgcn_s_setprio(0);\
    asm volatile("s_waitcnt vmcnt(" VMS ")" ::: "memory");                      \
    __builtin_amdgcn_s_barrier();                                               \
    /* ph3 */                                                                   \
    if (DORD) {                                                                 \
        _Pragma("unroll") for (int m = 0; m < 4; ++m) {                         \
            DSR(afA[m][0], ((CB) ^ SC_LDSB) + offA0 + m * 1024);                \
            DSR(afA[m][1], ((CB) ^ SC_LDSB) + offA1 + m * 1024); }              \
        DSR(bfr[0][0], ((CB) ^ SC_LDSB) + offB0);                               \
        DSR(bfr[0][1], ((CB) ^ SC_LDSB) + offB1);                               \
        DSR(bfr[1][0], ((CB) ^ SC_LDSB) + offB0 + 1024);                        \
        DSR(bfr[1][1], ((CB) ^ SC_LDSB) + offB1 + 1024);                        \
    }                                                                           \
    if (DOB) STB((CB), 1, (KT) + 2);                                            \
    __builtin_amdgcn_sched_barrier(0);                                          \
    __builtin_amdgcn_s_setprio(1); MQG(afB, 4, 2); __builtin_amdgcn_s_setprio(0);\
} while (0)

    bf16x8 afA[4][2];   // A rows 0-63 of wave's half (ping)
    bf16x8 afB[4][2];   // A rows 64-127 of wave's half (pong)
    bf16x8 bfr[4][2];
    f32x4  acc[8][4];
#pragma unroll
    for (int i = 0; i < 8; ++i)
#pragma unroll
        for (int j = 0; j < 4; ++j) { f32x4 z = {0.f, 0.f, 0.f, 0.f}; acc[i][j] = z; }

    // prologue: A(0),B(0) -> buf0; B(1) -> buf1; wait A0+B0 (leave B1 flying).
    STA(0, 0, 0); STA(0, 1, 0); STB(0, 0, 0); STB(0, 1, 0);
    STB(SC_LDSB, 0, 1); STB(SC_LDSB, 1, 1);
    asm volatile("s_waitcnt vmcnt(4)" ::: "memory");
    __builtin_amdgcn_s_barrier();
    // pre-reads ("ph3 of tile -1"): afA + bfr01 from buf0
#pragma unroll
    for (int m = 0; m < 4; ++m) {
        DSR(afA[m][0], offA0 + m * 1024);
        DSR(afA[m][1], offA1 + m * 1024);
    }
    DSR(bfr[0][0], offB0);        DSR(bfr[0][1], offB1);
    DSR(bfr[1][0], offB0 + 1024); DSR(bfr[1][1], offB1 + 1024);

#pragma unroll 1
    for (int tt = 0; tt < 14; tt += 2) {
        TILE(tt,     0,       1, 1, "2", 1);
        TILE(tt + 1, SC_LDSB, 1, 1, "2", 1);
    }
    TILE(14, 0,       1, 0, "0", 1);
    TILE(15, SC_LDSB, 0, 0, "0", 0);

    // epilogue: partial score = sum_u tanh(acc + projq[b][u]) * V[u]
    const int bq = mblk >> 3;                  // 8 mblks (of 256 rows) per batch
    const float* pq = projq + (size_t)bq * U_ + nblk * 256 + wn * 64;
    const float* Vp = V + nblk * 256 + wn * 64;
    float pqu[4], vu[4];
#pragma unroll
    for (int nt = 0; nt < 4; ++nt) { pqu[nt] = pq[nt * 16 + l15]; vu[nt] = Vp[nt * 16 + l15]; }
    const size_t rowbase = (size_t)mblk * 256 + (size_t)wm * 128;
#pragma unroll
    for (int mt = 0; mt < 8; ++mt) {
        float s0 = 0.f, s1 = 0.f, s2 = 0.f, s3 = 0.f;
#pragma unroll
        for (int nt = 0; nt < 4; ++nt) {
            s0 += tanh_fast(acc[mt][nt][0] + pqu[nt]) * vu[nt];
            s1 += tanh_fast(acc[mt][nt][1] + pqu[nt]) * vu[nt];
            s2 += tanh_fast(acc[mt][nt][2] + pqu[nt]) * vu[nt];
            s3 += tanh_fast(acc[mt][nt][3] + pqu[nt]) * vu[nt];
        }
        float s[4] = {s0, s1, s2, s3};
#pragma unroll
        for (int r = 0; r < 4; ++r) {
            float v = s[r];
            v += __shfl_xor(v, 1);
            v += __shfl_xor(v, 2);
            v += __shfl_xor(v, 4);
            v += __shfl_xor(v, 8);
            if (l15 == 0)
                atomicAdd(&score[rowbase + mt * 16 + quad * 4 + r], v);
        }
    }
#undef DSR
#undef STA
#undef STB
#undef MQG
#undef TILE
}

// ---------------- R1 fallback score GEMM (fp32 staging), if ws too small ----
__global__ __launch_bounds__(512, 2)
void score_kernel_f32(const float* __restrict__ values, const __bf16* __restrict__ W1T,
                      const float* __restrict__ projq, const float* __restrict__ V,
                      float* __restrict__ score) {
    __shared__ __attribute__((aligned(16))) __bf16 Al[64][40];
    __shared__ __attribute__((aligned(16))) __bf16 Bl[512][40];
    const int tid    = threadIdx.x;
    const int rowblk = blockIdx.x >> 1;
    const int nhalf  = blockIdx.x & 1;
    const int wave = tid >> 6, lane = tid & 63;
    const int quad = lane >> 4, l15 = lane & 15;
    const float*  Abase = values + (size_t)rowblk * 64 * D_;
    const __bf16* Bbase = W1T + (size_t)nhalf * 512 * D_;
    const int ar = tid >> 3, ac = (tid & 7) * 4;
    const int br = tid >> 2, bc = (tid & 3) * 8;
    f32x4 acc[4][4];
#pragma unroll
    for (int i = 0; i < 4; ++i)
#pragma unroll
        for (int j = 0; j < 4; ++j) { f32x4 z = {0.f,0.f,0.f,0.f}; acc[i][j] = z; }
    for (int kk = 0; kk < D_; kk += 32) {
        {
            const float4 v = *(const float4*)(Abase + (size_t)ar * D_ + kk + ac);
            bf16x4 h;
            h[0] = (__bf16)v.x; h[1] = (__bf16)v.y; h[2] = (__bf16)v.z; h[3] = (__bf16)v.w;
            *(bf16x4*)(&Al[ar][ac]) = h;
        }
#pragma unroll
        for (int p = 0; p < 4; ++p) {
            const int rr = p * 128 + br;
            const bf16x8 w = *(const bf16x8*)(Bbase + (size_t)rr * D_ + kk + bc);
            *(bf16x8*)(&Bl[rr][bc]) = w;
        }
        __syncthreads();
        bf16x8 af[4];
#pragma unroll
        for (int mt = 0; mt < 4; ++mt)
            af[mt] = *(const bf16x8*)(&Al[mt * 16 + l15][quad * 8]);
#pragma unroll
        for (int nt = 0; nt < 4; ++nt) {
            const bf16x8 bfr = *(const bf16x8*)(&Bl[wave * 64 + nt * 16 + l15][quad * 8]);
#pragma unroll
            for (int mt = 0; mt < 4; ++mt)
                acc[mt][nt] = __builtin_amdgcn_mfma_f32_16x16x32_bf16(af[mt], bfr, acc[mt][nt], 0, 0, 0);
        }
        __syncthreads();
    }
    const int b = rowblk >> 5;
    const size_t rowbase = (size_t)rowblk * 64;
    const float* pq = projq + (size_t)b * U_;
    const int ub = nhalf * 512 + wave * 64;
#pragma unroll
    for (int mt = 0; mt < 4; ++mt) {
        float s0 = 0.f, s1 = 0.f, s2 = 0.f, s3 = 0.f;
#pragma unroll
        for (int nt = 0; nt < 4; ++nt) {
            const int u = ub + nt * 16 + l15;
            const float pqu = pq[u];
            const float vu  = V[u];
            s0 += tanh_fast(acc[mt][nt][0] + pqu) * vu;
            s1 += tanh_fast(acc[mt][nt][1] + pqu) * vu;
            s2 += tanh_fast(acc[mt][nt][2] + pqu) * vu;
            s3 += tanh_fast(acc[mt][nt][3] + pqu) * vu;
        }
        float s[4] = {s0, s1, s2, s3};
#pragma unroll
        for (int r = 0; r < 4; ++r) {
            float v = s[r];
            v += __shfl_xor(v, 1);
            v += __shfl_xor(v, 2);
            v += __shfl_xor(v, 4);
            v += __shfl_xor(v, 8);
            if (l15 == 0)
                atomicAdd(&score[rowbase + mt * 16 + quad * 4 + r], v);
        }
    }
}

// ---------------- softmax over T (masked), writes attention weights ----------------
__global__ void softmax_kernel(const float* __restrict__ score, const float* __restrict__ mask,
                               const float* __restrict__ bV, float* __restrict__ out) {
    const int b = blockIdx.x;     // 32
    const int tid = threadIdx.x;  // 256
    const float bv = bV[0];
    float s[8];
    float lmax = -3.0e38f;
#pragma unroll
    for (int i = 0; i < 8; ++i) {
        const int t = tid + i * 256;
        const float v = score[(size_t)b * T_ + t] + bv + mask[(size_t)b * T_ + t] * (-1.0e9f);
        s[i] = v;
        lmax = fmaxf(lmax, v);
    }
#pragma unroll
    for (int m = 1; m < 64; m <<= 1) lmax = fmaxf(lmax, __shfl_xor(lmax, m));
    __shared__ float redm[4], reds[4];
    if ((tid & 63) == 0) redm[tid >> 6] = lmax;
    __syncthreads();
    const float M = fmaxf(fmaxf(redm[0], redm[1]), fmaxf(redm[2], redm[3]));
    float lsum = 0.f;
#pragma unroll
    for (int i = 0; i < 8; ++i) { s[i] = __expf(s[i] - M); lsum += s[i]; }
#pragma unroll
    for (int m = 1; m < 64; m <<= 1) lsum += __shfl_xor(lsum, m);
    if ((tid & 63) == 0) reds[tid >> 6] = lsum;
    __syncthreads();
    const float inv = 1.0f / (reds[0] + reds[1] + reds[2] + reds[3]);
#pragma unroll
    for (int i = 0; i < 8; ++i)
        out[(size_t)B_ * D_ + (size_t)b * T_ + tid + i * 256] = s[i] * inv;
}

// ---------------- context = sum_t attn[b,t] * valb[b,t,:]  (bf16 values) ----
__global__ void context_kernel_bf16(const __bf16* __restrict__ valb, const float* __restrict__ attn,
                                    float* __restrict__ out) {
    const int b  = blockIdx.x >> 4;   // 32
    const int dc = blockIdx.x & 15;   // 16 chunks of 64 d
    const int tid = threadIdx.x;      // 256
    __shared__ float a[T_];
#pragma unroll
    for (int i = 0; i < 8; ++i) a[tid + i * 256] = attn[(size_t)b * T_ + tid + i * 256];
    __syncthreads();
    const int dl = (tid & 7) * 8;     // 8 bf16 (16 B) per thread
    const int tg = tid >> 3;          // 0..31
    const __bf16* vb = valb + (size_t)b * T_ * D_ + dc * 64 + dl;
    float acc[8];
#pragma unroll
    for (int j = 0; j < 8; ++j) acc[j] = 0.f;
#pragma unroll 4
    for (int t = tg; t < T_; t += 32) {
        const bf16x8 v = *(const bf16x8*)(vb + (size_t)t * D_);
        const float w = a[t];
#pragma unroll
        for (int j = 0; j < 8; ++j) acc[j] = fmaf(w, (float)v[j], acc[j]);
    }
    __shared__ __attribute__((aligned(16))) float red[32][65];
#pragma unroll
    for (int j = 0; j < 8; ++j) red[tg][dl + j] = acc[j];
    __syncthreads();
    if (tid < 64) {
        float s = 0.f;
#pragma unroll
        for (int g = 0; g < 32; ++g) s += red[g][tid];
        out[(size_t)b * D_ + dc * 64 + tid] = s;
    }
}

// ---------------- fallback context (fp32 values) ----------------
__global__ void context_kernel(const float* __restrict__ values, const float* __restrict__ attn,
                               float* __restrict__ out) {
    const int b  = blockIdx.x >> 4;   // 32
    const int dc = blockIdx.x & 15;   // 16 chunks of 64 d
    const int tid = threadIdx.x;      // 256
    __shared__ float a[T_];
#pragma unroll
    for (int i = 0; i < 8; ++i) a[tid + i * 256] = attn[(size_t)b * T_ + tid + i * 256];
    __syncthreads();
    const int dl = (tid & 15) * 4;    // 64 d per block, float4 per thread
    const int tg = tid >> 4;          // 0..15
    const float* vb = values + (size_t)b * T_ * D_ + dc * 64 + dl;
    f32x4 acc = {0.f, 0.f, 0.f, 0.f};
#pragma unroll 4
    for (int t = tg; t < T_; t += 16) {
        const float4 v = *(const float4*)(vb + (size_t)t * D_);
        const float w = a[t];
        acc[0] = fmaf(w, v.x, acc[0]);
        acc[1] = fmaf(w, v.y, acc[1]);
        acc[2] = fmaf(w, v.z, acc[2]);
        acc[3] = fmaf(w, v.w, acc[3]);
    }
    __shared__ __attribute__((aligned(16))) float red[16][64];
    *(f32x4*)(&red[tg][dl]) = acc;
    __syncthreads();
    if (tid < 64) {
        float s = 0.f;
#pragma unroll
        for (int g = 0; g < 16; ++g) s += red[g][tid];
        out[(size_t)b * D_ + dc * 64 + tid] = s;
    }
}

extern "C" void kernel_launch(void* const* d_in, const int* in_sizes, int n_in,
                              void* d_out, int out_size, void* d_ws, size_t ws_size,
                              hipStream_t stream) {
    const float* values = (const float*)d_in[0];
    const float* query  = (const float*)d_in[1];
    const float* mask   = (const float*)d_in[2];
    const float* W1     = (const float*)d_in[3];
    const float* b1     = (const float*)d_in[4];
    const float* W2     = (const float*)d_in[5];
    const float* b2     = (const float*)d_in[6];
    const float* V      = (const float*)d_in[7];
    const float* bV     = (const float*)d_in[8];
    float* out = (float*)d_out;

    char* ws = (char*)d_ws;
    __bf16* W1T   = (__bf16*)(ws + WS_W1T);
    float*  projq = (float*)(ws + WS_PROJQ);
    float*  score = (float*)(ws + WS_SCORE);
    __bf16* valb  = (__bf16*)(ws + WS_VALB);

    init_kernel<<<dim3(384), dim3(256), 0, stream>>>(b1, b2, projq, score);
    w1_transpose_kernel<<<dim3(256), dim3(256), 0, stream>>>(W1, W1T);
    projq_kernel<<<dim3(256), dim3(256), 0, stream>>>(query, W2, projq);
    if (ws_size >= WS_NEEDED) {
        convert_kernel<<<dim3(32768), dim3(256), 0, stream>>>(values, valb);
        score_kernel_ra<<<dim3(1024), dim3(512), 0, stream>>>(valb, W1T, projq, V, score);
        softmax_kernel<<<dim3(32), dim3(256), 0, stream>>>(score, mask, bV, out);
        context_kernel_bf16<<<dim3(512), dim3(256), 0, stream>>>(valb, out + B_ * D_, out);
    } else {
        score_kernel_f32<<<dim3(2048), dim3(512), 0, stream>>>(values, W1T, projq, V, score);
        softmax_kernel<<<dim3(32), dim3(256), 0, stream>>>(score, mask, bV, out);
        context_kernel<<<dim3(512), dim3(256), 0, stream>>>(values, out + B_ * D_, out);
    }
}

// Round 4
// 606.269 us; speedup vs baseline: 1.4012x; 1.4012x over previous
//
#include <hip/hip_runtime.h>
#include <hip/hip_bf16.h>

// Bahdanau attention, MI355X. B=32, T=2048, D=1024, U=1024.
// R7: occupancy route. R5/R6's read-ahead spilled registers (FETCH 110->349MB,
// WRITE 39->143MB = scratch traffic; frag set 96+addr > 128 arch VGPR at
// acc[8][4]=128). Instead of ILP, restore TLP (m97/m114 mechanism):
//   - wave tile 64x64 (acc 64 regs), block 128(M)x256(N), 8 waves, BK=32
//   - LDS 2 x {A 128x32, B 256x32} bf16 = 48 KB -> 2 blocks/CU at
//     __launch_bounds__(512,4); cross-block overlap hides vmcnt(0)+barrier
//   - ONE __syncthreads() per K-step (double-buffer: stage next -> read cur)
//   - conflict-free slot swizzle for 32-col tiles: slot ^= (row>>1)&3
//     (2-way = free per m136), pre-swizzled global source + swizzled read
//   - plain HIP LDS reads (compiler emits fine-grained lgkmcnt) + glls16
// R3's real bottleneck was LDS bank conflict (8-way on [128][32]); R4 fixed
// that but dropped to 1 blk/CU (no TLP). This keeps both fixes.

typedef __bf16 bf16x8 __attribute__((ext_vector_type(8)));
typedef __bf16 bf16x4 __attribute__((ext_vector_type(4)));
typedef float  f32x4  __attribute__((ext_vector_type(4)));

#define B_  32
#define T_  2048
#define D_  1024
#define U_  1024
#define BT_ (B_*T_)

// ws layout (bytes)
#define WS_W1T    ((size_t)0)                          // 2 MiB bf16 [U][D]
#define WS_PROJQ  ((size_t)(2u*1024*1024))             // 128 KiB fp32 [B][U]
#define WS_SCORE  ((size_t)(2u*1024*1024 + 128u*1024)) // 256 KiB fp32 [B*T]
#define WS_VALB   ((size_t)(4u*1024*1024))             // 128 MiB bf16 [BT][D]
#define WS_NEEDED (WS_VALB + (size_t)BT_ * D_ * 2)

__device__ __forceinline__ float tanh_fast(float x) {
    const float e = __expf(2.0f * x);
    return 1.0f - __fdividef(2.0f, e + 1.0f);
}

__device__ __forceinline__ void glls16(const void* g, void* l) {
    __builtin_amdgcn_global_load_lds(
        (const __attribute__((address_space(1))) void*)g,
        (__attribute__((address_space(3))) void*)l, 16, 0, 0);
}

// ---------------- init: projq = b1+b2 (broadcast), score = 0 ----------------
__global__ void init_kernel(const float* __restrict__ b1, const float* __restrict__ b2,
                            float* __restrict__ projq, float* __restrict__ score) {
    int i = blockIdx.x * 256 + threadIdx.x;       // grid 384*256 = 98304 exact
    if (i < B_ * U_) {
        projq[i] = b1[i & (U_ - 1)] + b2[i & (U_ - 1)];
    } else {
        score[i - B_ * U_] = 0.0f;
    }
}

// ---------------- values fp32 -> bf16 (streaming) ----------------
__global__ void convert_kernel(const float* __restrict__ v, __bf16* __restrict__ o) {
    const size_t i = ((size_t)blockIdx.x * 256 + threadIdx.x) * 8;   // grid 32768
    const float4 a = *(const float4*)(v + i);
    const float4 b = *(const float4*)(v + i + 4);
    bf16x8 h;
    h[0] = (__bf16)a.x; h[1] = (__bf16)a.y; h[2] = (__bf16)a.z; h[3] = (__bf16)a.w;
    h[4] = (__bf16)b.x; h[5] = (__bf16)b.y; h[6] = (__bf16)b.z; h[7] = (__bf16)b.w;
    *(bf16x8*)(o + i) = h;
}

// ---------------- W1 [D][U] fp32 -> W1T [U][D] bf16 ----------------
__global__ void w1_transpose_kernel(const float* __restrict__ W1, __bf16* __restrict__ W1T) {
    __shared__ float tile[64][65];
    const int bx = blockIdx.x & 15;   // u tile
    const int by = blockIdx.x >> 4;   // d tile
    const int tid = threadIdx.x;      // 256
    const int j  = tid & 63;
    const int i0 = tid >> 6;          // 0..3
#pragma unroll
    for (int p = 0; p < 16; ++p) {
        const int i = i0 + p * 4;
        tile[i][j] = W1[(size_t)(by * 64 + i) * U_ + bx * 64 + j];
    }
    __syncthreads();
#pragma unroll
    for (int p = 0; p < 16; ++p) {
        const int i = i0 + p * 4;     // local u row
        W1T[(size_t)(bx * 64 + i) * D_ + by * 64 + j] = (__bf16)tile[j][i];
    }
}

// ---------------- projq += query @ W2 (fp32, d-split + atomics) ----------------
__global__ void projq_kernel(const float* __restrict__ query, const float* __restrict__ W2,
                             float* __restrict__ projq) {
    __shared__ float q[128];
    const int b  = blockIdx.x >> 3;   // 32
    const int dc = blockIdx.x & 7;    // 8 chunks of 128 d
    const int tid = threadIdx.x;      // 256
    if (tid < 128) q[tid] = query[(size_t)b * D_ + dc * 128 + tid];
    __syncthreads();
    const int u0 = tid * 4;
    float a0 = 0.f, a1 = 0.f, a2 = 0.f, a3 = 0.f;
    for (int d = 0; d < 128; ++d) {
        const float4 w = *(const float4*)(W2 + (size_t)(dc * 128 + d) * U_ + u0);
        const float qd = q[d];
        a0 = fmaf(qd, w.x, a0); a1 = fmaf(qd, w.y, a1);
        a2 = fmaf(qd, w.z, a2); a3 = fmaf(qd, w.w, a3);
    }
    float* p = projq + (size_t)b * U_ + u0;
    atomicAdd(p + 0, a0); atomicAdd(p + 1, a1);
    atomicAdd(p + 2, a2); atomicAdd(p + 3, a3);
}

// ---------------- fused score GEMM: 128x256 tile, 2 blocks/CU ----------------
// Grid 2048 = 512 mblk x 4 nblk, XCD-swizzled (the 4 nblks + neighbor mblks
// sharing an A-panel are co-XCD & temporally adjacent -> L2 reuse).
// 512 threads = 8 waves (2M x 4N), wave tile 64x64, acc[4][4]=64 regs.
// LDS per buffer: A[128][32] @0 (4096 el), B[256][32] @4096 (8192 el);
// two buffers at 0 / SC_BUF. One barrier per K-step.
// Swizzle: 64B rows, 4x16B slots; phys_slot = log_slot ^ ((row>>1)&3).
// Read (l15 spans 16 rows): positions (row parity x slot) = 8 distinct
// bank-groups -> 2 lanes each = conflict-free.

#define SC_A_ELE 4096            // 128*32
#define SC_B_ELE 8192            // 256*32
#define SC_BUF   (SC_A_ELE + SC_B_ELE)   // 12288 elems = 24 KiB

__global__ __launch_bounds__(512, 4)
void score_kernel_occ(const __bf16* __restrict__ valb, const __bf16* __restrict__ W1T,
                      const float* __restrict__ projq, const float* __restrict__ V,
                      float* __restrict__ score) {
    __shared__ __attribute__((aligned(16))) __bf16 lds[2 * SC_BUF];  // 48 KiB

    const int tid  = threadIdx.x;
    const int bid  = blockIdx.x;
    const int xcd  = bid & 7;
    const int sl   = bid >> 3;            // 0..255
    const int mblk = xcd * 64 + (sl >> 2);  // 0..511 (128 rows each)
    const int nblk = sl & 3;                // 256 cols each

    const int wv   = tid >> 6;            // wave 0..7
    const int lane = tid & 63;
    const int wm   = wv >> 2;             // 0..1 : 64-row slice
    const int wn   = wv & 3;              // 0..3 : 64-col slice
    const int l15  = lane & 15, quad = lane >> 4;

    // read-side swizzled slot (elems)
    const int rslot = (quad ^ ((l15 >> 1) & 3)) * 8;

    // staging: lane covers row (wv*16 + lane>>2), phys slot (lane&3);
    // logical (pre-swizzled) source slot = (lane&3) ^ ((srow>>1)&3)
    const int srow = lane >> 2;           // 0..15
    const int slog = ((lane & 3) ^ ((srow >> 1) & 3)) * 8;
    const __bf16* aS = valb + ((size_t)mblk * 128 + wv * 16 + srow) * D_ + slog;
    const __bf16* bS = W1T  + ((size_t)nblk * 256 + wv * 16 + srow) * D_ + slog;
    __bf16* aD = lds + wv * 512;                 // + cb
    __bf16* bD = lds + SC_A_ELE + wv * 512;      // + cb (+4096 for rows 128..255)

#define STAGE(CB, KT) do {                                                      \
    glls16(aS + (KT) * 32,                    aD + (CB));                       \
    glls16(bS + (KT) * 32,                    bD + (CB));                       \
    glls16(bS + (size_t)128 * D_ + (KT) * 32, bD + (CB) + 4096);                \
    } while (0)

#define BODY(KT, CB, DOS) do {                                                  \
    if (DOS) STAGE((CB) ^ SC_BUF, (KT) + 1);                                    \
    bf16x8 af[4], bf[4];                                                        \
    _Pragma("unroll")                                                           \
    for (int mt = 0; mt < 4; ++mt)                                              \
        af[mt] = *(const bf16x8*)(lds + (CB) +                                  \
                   (wm * 64 + mt * 16 + l15) * 32 + rslot);                     \
    _Pragma("unroll")                                                           \
    for (int nt = 0; nt < 4; ++nt)                                              \
        bf[nt] = *(const bf16x8*)(lds + (CB) + SC_A_ELE +                       \
                   (wn * 64 + nt * 16 + l15) * 32 + rslot);                     \
    _Pragma("unroll")                                                           \
    for (int nt = 0; nt < 4; ++nt)                                              \
    _Pragma("unroll")                                                           \
    for (int mt = 0; mt < 4; ++mt)                                              \
        acc[mt][nt] = __builtin_amdgcn_mfma_f32_16x16x32_bf16(                  \
            af[mt], bf[nt], acc[mt][nt], 0, 0, 0);                              \
    __syncthreads();                                                            \
    } while (0)

    f32x4 acc[4][4];
#pragma unroll
    for (int i = 0; i < 4; ++i)
#pragma unroll
        for (int j = 0; j < 4; ++j) { f32x4 z = {0.f, 0.f, 0.f, 0.f}; acc[i][j] = z; }

    // prologue: tile 0 -> buf 0
    STAGE(0, 0);
    __syncthreads();

#pragma unroll 1
    for (int kt = 0; kt < 32; kt += 2) {
        BODY(kt,     0,      1);
        BODY(kt + 1, SC_BUF, (kt + 1) < 31);
    }

    // epilogue: partial score = sum_u tanh(acc + projq[b][u]) * V[u]
    const int bq = mblk >> 4;                  // 16 mblks (of 128 rows) per batch
    const float* pq = projq + (size_t)bq * U_ + nblk * 256 + wn * 64;
    const float* Vp = V + nblk * 256 + wn * 64;
    float pqu[4], vu[4];
#pragma unroll
    for (int nt = 0; nt < 4; ++nt) { pqu[nt] = pq[nt * 16 + l15]; vu[nt] = Vp[nt * 16 + l15]; }
    const size_t rowbase = (size_t)mblk * 128 + (size_t)wm * 64;
#pragma unroll
    for (int mt = 0; mt < 4; ++mt) {
        float s0 = 0.f, s1 = 0.f, s2 = 0.f, s3 = 0.f;
#pragma unroll
        for (int nt = 0; nt < 4; ++nt) {
            s0 += tanh_fast(acc[mt][nt][0] + pqu[nt]) * vu[nt];
            s1 += tanh_fast(acc[mt][nt][1] + pqu[nt]) * vu[nt];
            s2 += tanh_fast(acc[mt][nt][2] + pqu[nt]) * vu[nt];
            s3 += tanh_fast(acc[mt][nt][3] + pqu[nt]) * vu[nt];
        }
        float s[4] = {s0, s1, s2, s3};
#pragma unroll
        for (int r = 0; r < 4; ++r) {
            float v = s[r];
            v += __shfl_xor(v, 1);
            v += __shfl_xor(v, 2);
            v += __shfl_xor(v, 4);
            v += __shfl_xor(v, 8);
            if (l15 == 0)
                atomicAdd(&score[rowbase + mt * 16 + quad * 4 + r], v);
        }
    }
#undef STAGE
#undef BODY
}

// ---------------- R1 fallback score GEMM (fp32 staging), if ws too small ----
__global__ __launch_bounds__(512, 2)
void score_kernel_f32(const float* __restrict__ values, const __bf16* __restrict__ W1T,
                      const float* __restrict__ projq, const float* __restrict__ V,
                      float* __restrict__ score) {
    __shared__ __attribute__((aligned(16))) __bf16 Al[64][40];
    __shared__ __attribute__((aligned(16))) __bf16 Bl[512][40];
    const int tid    = threadIdx.x;
    const int rowblk = blockIdx.x >> 1;
    const int nhalf  = blockIdx.x & 1;
    const int wave = tid >> 6, lane = tid & 63;
    const int quad = lane >> 4, l15 = lane & 15;
    const float*  Abase = values + (size_t)rowblk * 64 * D_;
    const __bf16* Bbase = W1T + (size_t)nhalf * 512 * D_;
    const int ar = tid >> 3, ac = (tid & 7) * 4;
    const int br = tid >> 2, bc = (tid & 3) * 8;
    f32x4 acc[4][4];
#pragma unroll
    for (int i = 0; i < 4; ++i)
#pragma unroll
        for (int j = 0; j < 4; ++j) { f32x4 z = {0.f,0.f,0.f,0.f}; acc[i][j] = z; }
    for (int kk = 0; kk < D_; kk += 32) {
        {
            const float4 v = *(const float4*)(Abase + (size_t)ar * D_ + kk + ac);
            bf16x4 h;
            h[0] = (__bf16)v.x; h[1] = (__bf16)v.y; h[2] = (__bf16)v.z; h[3] = (__bf16)v.w;
            *(bf16x4*)(&Al[ar][ac]) = h;
        }
#pragma unroll
        for (int p = 0; p < 4; ++p) {
            const int rr = p * 128 + br;
            const bf16x8 w = *(const bf16x8*)(Bbase + (size_t)rr * D_ + kk + bc);
            *(bf16x8*)(&Bl[rr][bc]) = w;
        }
        __syncthreads();
        bf16x8 af[4];
#pragma unroll
        for (int mt = 0; mt < 4; ++mt)
            af[mt] = *(const bf16x8*)(&Al[mt * 16 + l15][quad * 8]);
#pragma unroll
        for (int nt = 0; nt < 4; ++nt) {
            const bf16x8 bfr = *(const bf16x8*)(&Bl[wave * 64 + nt * 16 + l15][quad * 8]);
#pragma unroll
            for (int mt = 0; mt < 4; ++mt)
                acc[mt][nt] = __builtin_amdgcn_mfma_f32_16x16x32_bf16(af[mt], bfr, acc[mt][nt], 0, 0, 0);
        }
        __syncthreads();
    }
    const int b = rowblk >> 5;
    const size_t rowbase = (size_t)rowblk * 64;
    const float* pq = projq + (size_t)b * U_;
    const int ub = nhalf * 512 + wave * 64;
#pragma unroll
    for (int mt = 0; mt < 4; ++mt) {
        float s0 = 0.f, s1 = 0.f, s2 = 0.f, s3 = 0.f;
#pragma unroll
        for (int nt = 0; nt < 4; ++nt) {
            const int u = ub + nt * 16 + l15;
            const float pqu = pq[u];
            const float vu  = V[u];
            s0 += tanh_fast(acc[mt][nt][0] + pqu) * vu;
            s1 += tanh_fast(acc[mt][nt][1] + pqu) * vu;
            s2 += tanh_fast(acc[mt][nt][2] + pqu) * vu;
            s3 += tanh_fast(acc[mt][nt][3] + pqu) * vu;
        }
        float s[4] = {s0, s1, s2, s3};
#pragma unroll
        for (int r = 0; r < 4; ++r) {
            float v = s[r];
            v += __shfl_xor(v, 1);
            v += __shfl_xor(v, 2);
            v += __shfl_xor(v, 4);
            v += __shfl_xor(v, 8);
            if (l15 == 0)
                atomicAdd(&score[rowbase + mt * 16 + quad * 4 + r], v);
        }
    }
}

// ---------------- softmax over T (masked), writes attention weights ----------------
__global__ void softmax_kernel(const float* __restrict__ score, const float* __restrict__ mask,
                               const float* __restrict__ bV, float* __restrict__ out) {
    const int b = blockIdx.x;     // 32
    const int tid = threadIdx.x;  // 256
    const float bv = bV[0];
    float s[8];
    float lmax = -3.0e38f;
#pragma unroll
    for (int i = 0; i < 8; ++i) {
        const int t = tid + i * 256;
        const float v = score[(size_t)b * T_ + t] + bv + mask[(size_t)b * T_ + t] * (-1.0e9f);
        s[i] = v;
        lmax = fmaxf(lmax, v);
    }
#pragma unroll
    for (int m = 1; m < 64; m <<= 1) lmax = fmaxf(lmax, __shfl_xor(lmax, m));
    __shared__ float redm[4], reds[4];
    if ((tid & 63) == 0) redm[tid >> 6] = lmax;
    __syncthreads();
    const float M = fmaxf(fmaxf(redm[0], redm[1]), fmaxf(redm[2], redm[3]));
    float lsum = 0.f;
#pragma unroll
    for (int i = 0; i < 8; ++i) { s[i] = __expf(s[i] - M); lsum += s[i]; }
#pragma unroll
    for (int m = 1; m < 64; m <<= 1) lsum += __shfl_xor(lsum, m);
    if ((tid & 63) == 0) reds[tid >> 6] = lsum;
    __syncthreads();
    const float inv = 1.0f / (reds[0] + reds[1] + reds[2] + reds[3]);
#pragma unroll
    for (int i = 0; i < 8; ++i)
        out[(size_t)B_ * D_ + (size_t)b * T_ + tid + i * 256] = s[i] * inv;
}

// ---------------- context = sum_t attn[b,t] * valb[b,t,:]  (bf16 values) ----
__global__ void context_kernel_bf16(const __bf16* __restrict__ valb, const float* __restrict__ attn,
                                    float* __restrict__ out) {
    const int b  = blockIdx.x >> 4;   // 32
    const int dc = blockIdx.x & 15;   // 16 chunks of 64 d
    const int tid = threadIdx.x;      // 256
    __shared__ float a[T_];
#pragma unroll
    for (int i = 0; i < 8; ++i) a[tid + i * 256] = attn[(size_t)b * T_ + tid + i * 256];
    __syncthreads();
    const int dl = (tid & 7) * 8;     // 8 bf16 (16 B) per thread
    const int tg = tid >> 3;          // 0..31
    const __bf16* vb = valb + (size_t)b * T_ * D_ + dc * 64 + dl;
    float acc[8];
#pragma unroll
    for (int j = 0; j < 8; ++j) acc[j] = 0.f;
#pragma unroll 4
    for (int t = tg; t < T_; t += 32) {
        const bf16x8 v = *(const bf16x8*)(vb + (size_t)t * D_);
        const float w = a[t];
#pragma unroll
        for (int j = 0; j < 8; ++j) acc[j] = fmaf(w, (float)v[j], acc[j]);
    }
    __shared__ __attribute__((aligned(16))) float red[32][65];
#pragma unroll
    for (int j = 0; j < 8; ++j) red[tg][dl + j] = acc[j];
    __syncthreads();
    if (tid < 64) {
        float s = 0.f;
#pragma unroll
        for (int g = 0; g < 32; ++g) s += red[g][tid];
        out[(size_t)b * D_ + dc * 64 + tid] = s;
    }
}

// ---------------- fallback context (fp32 values) ----------------
__global__ void context_kernel(const float* __restrict__ values, const float* __restrict__ attn,
                               float* __restrict__ out) {
    const int b  = blockIdx.x >> 4;   // 32
    const int dc = blockIdx.x & 15;   // 16 chunks of 64 d
    const int tid = threadIdx.x;      // 256
    __shared__ float a[T_];
#pragma unroll
    for (int i = 0; i < 8; ++i) a[tid + i * 256] = attn[(size_t)b * T_ + tid + i * 256];
    __syncthreads();
    const int dl = (tid & 15) * 4;    // 64 d per block, float4 per thread
    const int tg = tid >> 4;          // 0..15
    const float* vb = values + (size_t)b * T_ * D_ + dc * 64 + dl;
    f32x4 acc = {0.f, 0.f, 0.f, 0.f};
#pragma unroll 4
    for (int t = tg; t < T_; t += 16) {
        const float4 v = *(const float4*)(vb + (size_t)t * D_);
        const float w = a[t];
        acc[0] = fmaf(w, v.x, acc[0]);
        acc[1] = fmaf(w, v.y, acc[1]);
        acc[2] = fmaf(w, v.z, acc[2]);
        acc[3] = fmaf(w, v.w, acc[3]);
    }
    __shared__ __attribute__((aligned(16))) float red[16][64];
    *(f32x4*)(&red[tg][dl]) = acc;
    __syncthreads();
    if (tid < 64) {
        float s = 0.f;
#pragma unroll
        for (int g = 0; g < 16; ++g) s += red[g][tid];
        out[(size_t)b * D_ + dc * 64 + tid] = s;
    }
}

extern "C" void kernel_launch(void* const* d_in, const int* in_sizes, int n_in,
                              void* d_out, int out_size, void* d_ws, size_t ws_size,
                              hipStream_t stream) {
    const float* values = (const float*)d_in[0];
    const float* query  = (const float*)d_in[1];
    const float* mask   = (const float*)d_in[2];
    const float* W1     = (const float*)d_in[3];
    const float* b1     = (const float*)d_in[4];
    const float* W2     = (const float*)d_in[5];
    const float* b2     = (const float*)d_in[6];
    const float* V      = (const float*)d_in[7];
    const float* bV     = (const float*)d_in[8];
    float* out = (float*)d_out;

    char* ws = (char*)d_ws;
    __bf16* W1T   = (__bf16*)(ws + WS_W1T);
    float*  projq = (float*)(ws + WS_PROJQ);
    float*  score = (float*)(ws + WS_SCORE);
    __bf16* valb  = (__bf16*)(ws + WS_VALB);

    init_kernel<<<dim3(384), dim3(256), 0, stream>>>(b1, b2, projq, score);
    w1_transpose_kernel<<<dim3(256), dim3(256), 0, stream>>>(W1, W1T);
    projq_kernel<<<dim3(256), dim3(256), 0, stream>>>(query, W2, projq);
    if (ws_size >= WS_NEEDED) {
        convert_kernel<<<dim3(32768), dim3(256), 0, stream>>>(values, valb);
        score_kernel_occ<<<dim3(2048), dim3(512), 0, stream>>>(valb, W1T, projq, V, score);
        softmax_kernel<<<dim3(32), dim3(256), 0, stream>>>(score, mask, bV, out);
        context_kernel_bf16<<<dim3(512), dim3(256), 0, stream>>>(valb, out + B_ * D_, out);
    } else {
        score_kernel_f32<<<dim3(2048), dim3(512), 0, stream>>>(values, W1T, projq, V, score);
        softmax_kernel<<<dim3(32), dim3(256), 0, stream>>>(score, mask, bV, out);
        context_kernel<<<dim3(512), dim3(256), 0, stream>>>(values, out + B_ * D_, out);
    }
}

// Round 5
// 593.281 us; speedup vs baseline: 1.4319x; 1.0219x over previous
//
#include <hip/hip_runtime.h>
#include <hip/hip_bf16.h>

// Bahdanau attention, MI355X. B=32, T=2048, D=1024, U=1024.
// R8 = R7 + {triple-buffer staging, raw s_barrier + counted vmcnt(3)}.
// R7 post-mortem: no spill (WRITE 16MB, VGPR 56) but Mfma 27% — the stall is
// __syncthreads()'s implicit vmcnt(0) draining glls16 batches issued at the
// TOP OF THE SAME K-step (HBM latency ~900-1500cyc on every step's critical
// path). Fix: stage K-step t+2 at step t (3 bufs x 24KB = 72KB, still 2
// blk/CU) and wait with counted vmcnt(3) (batch for t+1 was issued at t-1,
// ~3000cyc old -> wait is free). Raw s_barrier (no auto-drain) with memory-
// clobber brackets; plain-HIP ds_reads keep frag liveness low (VGPR 56-ish,
// 2 blocks/CU at __launch_bounds__(512,4)).
// vmcnt counting (3 glls16/batch/thread, in-order): steady state 6 in flight,
// vmcnt(3) drains the older batch; step 30 -> vmcnt(0); step 31 -> no wait.

typedef __bf16 bf16x8 __attribute__((ext_vector_type(8)));
typedef __bf16 bf16x4 __attribute__((ext_vector_type(4)));
typedef float  f32x4  __attribute__((ext_vector_type(4)));

#define B_  32
#define T_  2048
#define D_  1024
#define U_  1024
#define BT_ (B_*T_)

// ws layout (bytes)
#define WS_W1T    ((size_t)0)                          // 2 MiB bf16 [U][D]
#define WS_PROJQ  ((size_t)(2u*1024*1024))             // 128 KiB fp32 [B][U]
#define WS_SCORE  ((size_t)(2u*1024*1024 + 128u*1024)) // 256 KiB fp32 [B*T]
#define WS_VALB   ((size_t)(4u*1024*1024))             // 128 MiB bf16 [BT][D]
#define WS_NEEDED (WS_VALB + (size_t)BT_ * D_ * 2)

__device__ __forceinline__ float tanh_fast(float x) {
    const float e = __expf(2.0f * x);
    return 1.0f - __fdividef(2.0f, e + 1.0f);
}

__device__ __forceinline__ void glls16(const void* g, void* l) {
    __builtin_amdgcn_global_load_lds(
        (const __attribute__((address_space(1))) void*)g,
        (__attribute__((address_space(3))) void*)l, 16, 0, 0);
}

// ---------------- init: projq = b1+b2 (broadcast), score = 0 ----------------
__global__ void init_kernel(const float* __restrict__ b1, const float* __restrict__ b2,
                            float* __restrict__ projq, float* __restrict__ score) {
    int i = blockIdx.x * 256 + threadIdx.x;       // grid 384*256 = 98304 exact
    if (i < B_ * U_) {
        projq[i] = b1[i & (U_ - 1)] + b2[i & (U_ - 1)];
    } else {
        score[i - B_ * U_] = 0.0f;
    }
}

// ---------------- values fp32 -> bf16 (streaming) ----------------
__global__ void convert_kernel(const float* __restrict__ v, __bf16* __restrict__ o) {
    const size_t i = ((size_t)blockIdx.x * 256 + threadIdx.x) * 8;   // grid 32768
    const float4 a = *(const float4*)(v + i);
    const float4 b = *(const float4*)(v + i + 4);
    bf16x8 h;
    h[0] = (__bf16)a.x; h[1] = (__bf16)a.y; h[2] = (__bf16)a.z; h[3] = (__bf16)a.w;
    h[4] = (__bf16)b.x; h[5] = (__bf16)b.y; h[6] = (__bf16)b.z; h[7] = (__bf16)b.w;
    *(bf16x8*)(o + i) = h;
}

// ---------------- W1 [D][U] fp32 -> W1T [U][D] bf16 ----------------
__global__ void w1_transpose_kernel(const float* __restrict__ W1, __bf16* __restrict__ W1T) {
    __shared__ float tile[64][65];
    const int bx = blockIdx.x & 15;   // u tile
    const int by = blockIdx.x >> 4;   // d tile
    const int tid = threadIdx.x;      // 256
    const int j  = tid & 63;
    const int i0 = tid >> 6;          // 0..3
#pragma unroll
    for (int p = 0; p < 16; ++p) {
        const int i = i0 + p * 4;
        tile[i][j] = W1[(size_t)(by * 64 + i) * U_ + bx * 64 + j];
    }
    __syncthreads();
#pragma unroll
    for (int p = 0; p < 16; ++p) {
        const int i = i0 + p * 4;     // local u row
        W1T[(size_t)(bx * 64 + i) * D_ + by * 64 + j] = (__bf16)tile[j][i];
    }
}

// ---------------- projq += query @ W2 (fp32, d-split + atomics) ----------------
__global__ void projq_kernel(const float* __restrict__ query, const float* __restrict__ W2,
                             float* __restrict__ projq) {
    __shared__ float q[128];
    const int b  = blockIdx.x >> 3;   // 32
    const int dc = blockIdx.x & 7;    // 8 chunks of 128 d
    const int tid = threadIdx.x;      // 256
    if (tid < 128) q[tid] = query[(size_t)b * D_ + dc * 128 + tid];
    __syncthreads();
    const int u0 = tid * 4;
    float a0 = 0.f, a1 = 0.f, a2 = 0.f, a3 = 0.f;
    for (int d = 0; d < 128; ++d) {
        const float4 w = *(const float4*)(W2 + (size_t)(dc * 128 + d) * U_ + u0);
        const float qd = q[d];
        a0 = fmaf(qd, w.x, a0); a1 = fmaf(qd, w.y, a1);
        a2 = fmaf(qd, w.z, a2); a3 = fmaf(qd, w.w, a3);
    }
    float* p = projq + (size_t)b * U_ + u0;
    atomicAdd(p + 0, a0); atomicAdd(p + 1, a1);
    atomicAdd(p + 2, a2); atomicAdd(p + 3, a3);
}

// ---------------- fused score GEMM: 128x256 tile, 3-buf, 2 blocks/CU --------
// Grid 2048 = 512 mblk x 4 nblk, XCD-swizzled. 512 threads = 8 waves (2M x 4N),
// wave tile 64x64, acc[4][4]=64 AGPRs. LDS: 3 bufs x {A[128][32], B[256][32]}
// bf16 = 72 KiB. Per K-step t: stage t+2 -> buf (t+2)%3; read buf t%3; end
// with s_waitcnt vmcnt(3) + raw s_barrier (drains batch for t+1, issued t-1).
// Swizzle (R7, verified): 64B rows, 4x16B slots, phys = log ^ ((row>>1)&3).

#define SC_A_ELE 4096            // 128*32
#define SC_B_ELE 8192            // 256*32
#define SC_BUFE  (SC_A_ELE + SC_B_ELE)   // 12288 elems = 24 KiB per buffer

__global__ __launch_bounds__(512, 4)
void score_kernel_3buf(const __bf16* __restrict__ valb, const __bf16* __restrict__ W1T,
                       const float* __restrict__ projq, const float* __restrict__ V,
                       float* __restrict__ score) {
    __shared__ __attribute__((aligned(16))) __bf16 lds[3 * SC_BUFE];  // 72 KiB

    const int tid  = threadIdx.x;
    const int bid  = blockIdx.x;
    const int xcd  = bid & 7;
    const int sl   = bid >> 3;            // 0..255
    const int mblk = xcd * 64 + (sl >> 2);  // 0..511 (128 rows each)
    const int nblk = sl & 3;                // 256 cols each

    const int wv   = tid >> 6;            // wave 0..7
    const int lane = tid & 63;
    const int wm   = wv >> 2;             // 0..1 : 64-row slice
    const int wn   = wv & 3;              // 0..3 : 64-col slice
    const int l15  = lane & 15, quad = lane >> 4;

    // read-side swizzled slot (elems)
    const int rslot = (quad ^ ((l15 >> 1) & 3)) * 8;

    // staging: lane covers row (wv*16 + lane>>2), phys slot (lane&3);
    // logical (pre-swizzled) source slot = (lane&3) ^ ((srow>>1)&3)
    const int srow = lane >> 2;           // 0..15
    const int slog = ((lane & 3) ^ ((srow >> 1) & 3)) * 8;
    const __bf16* aS = valb + ((size_t)mblk * 128 + wv * 16 + srow) * D_ + slog;
    const __bf16* bS = W1T  + ((size_t)nblk * 256 + wv * 16 + srow) * D_ + slog;
    __bf16* aD = lds + wv * 512;                 // + cb
    __bf16* bD = lds + SC_A_ELE + wv * 512;      // + cb (+4096 for rows 128..255)

#define STAGE(CB, KT) do {                                                      \
    glls16(aS + (KT) * 32,                    aD + (CB));                       \
    glls16(bS + (KT) * 32,                    bD + (CB));                       \
    glls16(bS + (size_t)128 * D_ + (KT) * 32, bD + (CB) + 4096);                \
    } while (0)

// VM: 3 = steady counted wait; 0 = drain; -1 = none (last step)
#define STEP(KT, CBR, CBS, DOS, VM) do {                                        \
    if (DOS) STAGE((CBS), (KT) + 2);                                            \
    bf16x8 af[4], bf[4];                                                        \
    _Pragma("unroll")                                                           \
    for (int mt = 0; mt < 4; ++mt)                                              \
        af[mt] = *(const bf16x8*)(lds + (CBR) +                                 \
                   (wm * 64 + mt * 16 + l15) * 32 + rslot);                     \
    _Pragma("unroll")                                                           \
    for (int nt = 0; nt < 4; ++nt)                                              \
        bf[nt] = *(const bf16x8*)(lds + (CBR) + SC_A_ELE +                      \
                   (wn * 64 + nt * 16 + l15) * 32 + rslot);                     \
    _Pragma("unroll")                                                           \
    for (int nt = 0; nt < 4; ++nt)                                              \
    _Pragma("unroll")                                                           \
    for (int mt = 0; mt < 4; ++mt)                                              \
        acc[mt][nt] = __builtin_amdgcn_mfma_f32_16x16x32_bf16(                  \
            af[mt], bf[nt], acc[mt][nt], 0, 0, 0);                              \
    if ((VM) >= 0) {                                                            \
        if ((VM) == 3) asm volatile("s_waitcnt vmcnt(3)" ::: "memory");         \
        else           asm volatile("s_waitcnt vmcnt(0)" ::: "memory");         \
        __builtin_amdgcn_s_barrier();                                           \
        asm volatile("" ::: "memory");                                          \
    }                                                                           \
    } while (0)

    f32x4 acc[4][4];
#pragma unroll
    for (int i = 0; i < 4; ++i)
#pragma unroll
        for (int j = 0; j < 4; ++j) { f32x4 z = {0.f, 0.f, 0.f, 0.f}; acc[i][j] = z; }

    // prologue: K-step 0 -> buf0, K-step 1 -> buf1; wait buf0 (leave buf1 flying)
    STAGE(0, 0);
    STAGE(SC_BUFE, 1);
    asm volatile("s_waitcnt vmcnt(3)" ::: "memory");
    __builtin_amdgcn_s_barrier();
    asm volatile("" ::: "memory");

#pragma unroll 1
    for (int t = 0; t < 30; t += 3) {
        STEP(t,     0,           2 * SC_BUFE, 1, 3);
        STEP(t + 1, SC_BUFE,     0,           1, 3);
        STEP(t + 2, 2 * SC_BUFE, SC_BUFE,     1, 3);
    }
    STEP(30, 0,       0, 0, 0);    // drain: buf31's batch (issued at step 29)
    STEP(31, SC_BUFE, 0, 0, -1);   // last step: no stage, no wait

    // epilogue: partial score = sum_u tanh(acc + projq[b][u]) * V[u]
    const int bq = mblk >> 4;                  // 16 mblks (of 128 rows) per batch
    const float* pq = projq + (size_t)bq * U_ + nblk * 256 + wn * 64;
    const float* Vp = V + nblk * 256 + wn * 64;
    float pqu[4], vu[4];
#pragma unroll
    for (int nt = 0; nt < 4; ++nt) { pqu[nt] = pq[nt * 16 + l15]; vu[nt] = Vp[nt * 16 + l15]; }
    const size_t rowbase = (size_t)mblk * 128 + (size_t)wm * 64;
#pragma unroll
    for (int mt = 0; mt < 4; ++mt) {
        float s0 = 0.f, s1 = 0.f, s2 = 0.f, s3 = 0.f;
#pragma unroll
        for (int nt = 0; nt < 4; ++nt) {
            s0 += tanh_fast(acc[mt][nt][0] + pqu[nt]) * vu[nt];
            s1 += tanh_fast(acc[mt][nt][1] + pqu[nt]) * vu[nt];
            s2 += tanh_fast(acc[mt][nt][2] + pqu[nt]) * vu[nt];
            s3 += tanh_fast(acc[mt][nt][3] + pqu[nt]) * vu[nt];
        }
        float s[4] = {s0, s1, s2, s3};
#pragma unroll
        for (int r = 0; r < 4; ++r) {
            float v = s[r];
            v += __shfl_xor(v, 1);
            v += __shfl_xor(v, 2);
            v += __shfl_xor(v, 4);
            v += __shfl_xor(v, 8);
            if (l15 == 0)
                atomicAdd(&score[rowbase + mt * 16 + quad * 4 + r], v);
        }
    }
#undef STAGE
#undef STEP
}

// ---------------- R1 fallback score GEMM (fp32 staging), if ws too small ----
__global__ __launch_bounds__(512, 2)
void score_kernel_f32(const float* __restrict__ values, const __bf16* __restrict__ W1T,
                      const float* __restrict__ projq, const float* __restrict__ V,
                      float* __restrict__ score) {
    __shared__ __attribute__((aligned(16))) __bf16 Al[64][40];
    __shared__ __attribute__((aligned(16))) __bf16 Bl[512][40];
    const int tid    = threadIdx.x;
    const int rowblk = blockIdx.x >> 1;
    const int nhalf  = blockIdx.x & 1;
    const int wave = tid >> 6, lane = tid & 63;
    const int quad = lane >> 4, l15 = lane & 15;
    const float*  Abase = values + (size_t)rowblk * 64 * D_;
    const __bf16* Bbase = W1T + (size_t)nhalf * 512 * D_;
    const int ar = tid >> 3, ac = (tid & 7) * 4;
    const int br = tid >> 2, bc = (tid & 3) * 8;
    f32x4 acc[4][4];
#pragma unroll
    for (int i = 0; i < 4; ++i)
#pragma unroll
        for (int j = 0; j < 4; ++j) { f32x4 z = {0.f,0.f,0.f,0.f}; acc[i][j] = z; }
    for (int kk = 0; kk < D_; kk += 32) {
        {
            const float4 v = *(const float4*)(Abase + (size_t)ar * D_ + kk + ac);
            bf16x4 h;
            h[0] = (__bf16)v.x; h[1] = (__bf16)v.y; h[2] = (__bf16)v.z; h[3] = (__bf16)v.w;
            *(bf16x4*)(&Al[ar][ac]) = h;
        }
#pragma unroll
        for (int p = 0; p < 4; ++p) {
            const int rr = p * 128 + br;
            const bf16x8 w = *(const bf16x8*)(Bbase + (size_t)rr * D_ + kk + bc);
            *(bf16x8*)(&Bl[rr][bc]) = w;
        }
        __syncthreads();
        bf16x8 af[4];
#pragma unroll
        for (int mt = 0; mt < 4; ++mt)
            af[mt] = *(const bf16x8*)(&Al[mt * 16 + l15][quad * 8]);
#pragma unroll
        for (int nt = 0; nt < 4; ++nt) {
            const bf16x8 bfr = *(const bf16x8*)(&Bl[wave * 64 + nt * 16 + l15][quad * 8]);
#pragma unroll
            for (int mt = 0; mt < 4; ++mt)
                acc[mt][nt] = __builtin_amdgcn_mfma_f32_16x16x32_bf16(af[mt], bfr, acc[mt][nt], 0, 0, 0);
        }
        __syncthreads();
    }
    const int b = rowblk >> 5;
    const size_t rowbase = (size_t)rowblk * 64;
    const float* pq = projq + (size_t)b * U_;
    const int ub = nhalf * 512 + wave * 64;
#pragma unroll
    for (int mt = 0; mt < 4; ++mt) {
        float s0 = 0.f, s1 = 0.f, s2 = 0.f, s3 = 0.f;
#pragma unroll
        for (int nt = 0; nt < 4; ++nt) {
            const int u = ub + nt * 16 + l15;
            const float pqu = pq[u];
            const float vu  = V[u];
            s0 += tanh_fast(acc[mt][nt][0] + pqu) * vu;
            s1 += tanh_fast(acc[mt][nt][1] + pqu) * vu;
            s2 += tanh_fast(acc[mt][nt][2] + pqu) * vu;
            s3 += tanh_fast(acc[mt][nt][3] + pqu) * vu;
        }
        float s[4] = {s0, s1, s2, s3};
#pragma unroll
        for (int r = 0; r < 4; ++r) {
            float v = s[r];
            v += __shfl_xor(v, 1);
            v += __shfl_xor(v, 2);
            v += __shfl_xor(v, 4);
            v += __shfl_xor(v, 8);
            if (l15 == 0)
                atomicAdd(&score[rowbase + mt * 16 + quad * 4 + r], v);
        }
    }
}

// ---------------- softmax over T (masked), writes attention weights ----------------
__global__ void softmax_kernel(const float* __restrict__ score, const float* __restrict__ mask,
                               const float* __restrict__ bV, float* __restrict__ out) {
    const int b = blockIdx.x;     // 32
    const int tid = threadIdx.x;  // 256
    const float bv = bV[0];
    float s[8];
    float lmax = -3.0e38f;
#pragma unroll
    for (int i = 0; i < 8; ++i) {
        const int t = tid + i * 256;
        const float v = score[(size_t)b * T_ + t] + bv + mask[(size_t)b * T_ + t] * (-1.0e9f);
        s[i] = v;
        lmax = fmaxf(lmax, v);
    }
#pragma unroll
    for (int m = 1; m < 64; m <<= 1) lmax = fmaxf(lmax, __shfl_xor(lmax, m));
    __shared__ float redm[4], reds[4];
    if ((tid & 63) == 0) redm[tid >> 6] = lmax;
    __syncthreads();
    const float M = fmaxf(fmaxf(redm[0], redm[1]), fmaxf(redm[2], redm[3]));
    float lsum = 0.f;
#pragma unroll
    for (int i = 0; i < 8; ++i) { s[i] = __expf(s[i] - M); lsum += s[i]; }
#pragma unroll
    for (int m = 1; m < 64; m <<= 1) lsum += __shfl_xor(lsum, m);
    if ((tid & 63) == 0) reds[tid >> 6] = lsum;
    __syncthreads();
    const float inv = 1.0f / (reds[0] + reds[1] + reds[2] + reds[3]);
#pragma unroll
    for (int i = 0; i < 8; ++i)
        out[(size_t)B_ * D_ + (size_t)b * T_ + tid + i * 256] = s[i] * inv;
}

// ---------------- context = sum_t attn[b,t] * valb[b,t,:]  (bf16 values) ----
__global__ void context_kernel_bf16(const __bf16* __restrict__ valb, const float* __restrict__ attn,
                                    float* __restrict__ out) {
    const int b  = blockIdx.x >> 4;   // 32
    const int dc = blockIdx.x & 15;   // 16 chunks of 64 d
    const int tid = threadIdx.x;      // 256
    __shared__ float a[T_];
#pragma unroll
    for (int i = 0; i < 8; ++i) a[tid + i * 256] = attn[(size_t)b * T_ + tid + i * 256];
    __syncthreads();
    const int dl = (tid & 7) * 8;     // 8 bf16 (16 B) per thread
    const int tg = tid >> 3;          // 0..31
    const __bf16* vb = valb + (size_t)b * T_ * D_ + dc * 64 + dl;
    float acc[8];
#pragma unroll
    for (int j = 0; j < 8; ++j) acc[j] = 0.f;
#pragma unroll 4
    for (int t = tg; t < T_; t += 32) {
        const bf16x8 v = *(const bf16x8*)(vb + (size_t)t * D_);
        const float w = a[t];
#pragma unroll
        for (int j = 0; j < 8; ++j) acc[j] = fmaf(w, (float)v[j], acc[j]);
    }
    __shared__ __attribute__((aligned(16))) float red[32][65];
#pragma unroll
    for (int j = 0; j < 8; ++j) red[tg][dl + j] = acc[j];
    __syncthreads();
    if (tid < 64) {
        float s = 0.f;
#pragma unroll
        for (int g = 0; g < 32; ++g) s += red[g][tid];
        out[(size_t)b * D_ + dc * 64 + tid] = s;
    }
}

// ---------------- fallback context (fp32 values) ----------------
__global__ void context_kernel(const float* __restrict__ values, const float* __restrict__ attn,
                               float* __restrict__ out) {
    const int b  = blockIdx.x >> 4;   // 32
    const int dc = blockIdx.x & 15;   // 16 chunks of 64 d
    const int tid = threadIdx.x;      // 256
    __shared__ float a[T_];
#pragma unroll
    for (int i = 0; i < 8; ++i) a[tid + i * 256] = attn[(size_t)b * T_ + tid + i * 256];
    __syncthreads();
    const int dl = (tid & 15) * 4;    // 64 d per block, float4 per thread
    const int tg = tid >> 4;          // 0..15
    const float* vb = values + (size_t)b * T_ * D_ + dc * 64 + dl;
    f32x4 acc = {0.f, 0.f, 0.f, 0.f};
#pragma unroll 4
    for (int t = tg; t < T_; t += 16) {
        const float4 v = *(const float4*)(vb + (size_t)t * D_);
        const float w = a[t];
        acc[0] = fmaf(w, v.x, acc[0]);
        acc[1] = fmaf(w, v.y, acc[1]);
        acc[2] = fmaf(w, v.z, acc[2]);
        acc[3] = fmaf(w, v.w, acc[3]);
    }
    __shared__ __attribute__((aligned(16))) float red[16][64];
    *(f32x4*)(&red[tg][dl]) = acc;
    __syncthreads();
    if (tid < 64) {
        float s = 0.f;
#pragma unroll
        for (int g = 0; g < 16; ++g) s += red[g][tid];
        out[(size_t)b * D_ + dc * 64 + tid] = s;
    }
}

extern "C" void kernel_launch(void* const* d_in, const int* in_sizes, int n_in,
                              void* d_out, int out_size, void* d_ws, size_t ws_size,
                              hipStream_t stream) {
    const float* values = (const float*)d_in[0];
    const float* query  = (const float*)d_in[1];
    const float* mask   = (const float*)d_in[2];
    const float* W1     = (const float*)d_in[3];
    const float* b1     = (const float*)d_in[4];
    const float* W2     = (const float*)d_in[5];
    const float* b2     = (const float*)d_in[6];
    const float* V      = (const float*)d_in[7];
    const float* bV     = (const float*)d_in[8];
    float* out = (float*)d_out;

    char* ws = (char*)d_ws;
    __bf16* W1T   = (__bf16*)(ws + WS_W1T);
    float*  projq = (float*)(ws + WS_PROJQ);
    float*  score = (float*)(ws + WS_SCORE);
    __bf16* valb  = (__bf16*)(ws + WS_VALB);

    init_kernel<<<dim3(384), dim3(256), 0, stream>>>(b1, b2, projq, score);
    w1_transpose_kernel<<<dim3(256), dim3(256), 0, stream>>>(W1, W1T);
    projq_kernel<<<dim3(256), dim3(256), 0, stream>>>(query, W2, projq);
    if (ws_size >= WS_NEEDED) {
        convert_kernel<<<dim3(32768), dim3(256), 0, stream>>>(values, valb);
        score_kernel_3buf<<<dim3(2048), dim3(512), 0, stream>>>(valb, W1T, projq, V, score);
        softmax_kernel<<<dim3(32), dim3(256), 0, stream>>>(score, mask, bV, out);
        context_kernel_bf16<<<dim3(512), dim3(256), 0, stream>>>(valb, out + B_ * D_, out);
    } else {
        score_kernel_f32<<<dim3(2048), dim3(512), 0, stream>>>(values, W1T, projq, V, score);
        softmax_kernel<<<dim3(32), dim3(256), 0, stream>>>(score, mask, bV, out);
        context_kernel<<<dim3(512), dim3(256), 0, stream>>>(values, out + B_ * D_, out);
    }
}